// Round 1
// baseline (395.674 us; speedup 1.0000x reference)
//
#include <hip/hip_runtime.h>

typedef short bf16x8 __attribute__((ext_vector_type(8)));
typedef float f32x4 __attribute__((ext_vector_type(4)));

#define K_CLUSTERS 512
#define DIM 64

__device__ __forceinline__ unsigned short f32_to_bf16_rne(float f) {
    unsigned int u = __float_as_uint(f);
    u += 0x7fffu + ((u >> 16) & 1u);
    return (unsigned short)(u >> 16);
}
__device__ __forceinline__ float bf16_bits_to_f32(unsigned short h) {
    return __uint_as_float(((unsigned int)h) << 16);
}

// Convert centers to bf16 hi/lo split + compute ||c||^2. One wave per cluster.
__global__ void prep_centers(const float* __restrict__ c,
                             short* __restrict__ c_hi, short* __restrict__ c_lo,
                             float* __restrict__ c_sq) {
    int idx = blockIdx.x * 256 + threadIdx.x;   // covers 512*64
    float v = c[idx];
    unsigned short h = f32_to_bf16_rne(v);
    float hf = bf16_bits_to_f32(h);
    unsigned short l = f32_to_bf16_rne(v - hf);
    c_hi[idx] = (short)h;
    c_lo[idx] = (short)l;
    float s = v * v;
    #pragma unroll
    for (int off = 1; off < 64; off <<= 1) s += __shfl_xor(s, off, 64);
    if ((threadIdx.x & 63) == 0) c_sq[idx >> 6] = s;
}

// 16 rows per block; 4 waves x 128 clusters each; fused dist+softmax+loss.
__global__ __launch_bounds__(256, 2)
void cluster_kernel(const float* __restrict__ z,
                    const short* __restrict__ c_hi,
                    const short* __restrict__ c_lo,
                    const float* __restrict__ c_sq,
                    float* __restrict__ q_out,
                    float* __restrict__ partials) {
    __shared__ __align__(16) short a_hi_s[16][72];   // stride 144B: 16B-aligned rows
    __shared__ __align__(16) short a_lo_s[16][72];
    __shared__ float zsq_s[16];
    __shared__ float dist_s[16][K_CLUSTERS + 4];
    __shared__ float wloss_s[4];

    const int tid  = threadIdx.x;
    const int lane = tid & 63;
    const int wave = tid >> 6;
    const int m    = lane & 15;   // A row / B,C col within tile
    const int qd   = lane >> 4;   // quad
    const long rb  = (long)blockIdx.x * 16;

    // ---- B fragments from global (bf16, cached in L1/L2). B[k][n] = c[n][k]:
    // lane n holds c[col][kg*32 + qd*8 .. +8) -> contiguous 16B. ----
    bf16x8 bh[8][2], bl[8][2];
    #pragma unroll
    for (int t = 0; t < 8; ++t) {
        const int col = wave * 128 + t * 16 + m;
        const long boff = (long)col * DIM + qd * 8;
        #pragma unroll
        for (int kg = 0; kg < 2; ++kg) {
            bh[t][kg] = *(const bf16x8*)(c_hi + boff + kg * 32);
            bl[t][kg] = *(const bf16x8*)(c_lo + boff + kg * 32);
        }
    }

    // ---- stage A tile: 16 rows x 64 dims, fp32 -> bf16 hi/lo, plus ||z||^2 ----
    {
        float4 v = ((const float4*)(z + rb * DIM))[tid];   // coalesced 4KB
        const int srow = tid >> 4;
        const int scol = (tid & 15) * 4;
        float fv[4] = {v.x, v.y, v.z, v.w};
        #pragma unroll
        for (int j = 0; j < 4; ++j) {
            unsigned short h = f32_to_bf16_rne(fv[j]);
            float hf = bf16_bits_to_f32(h);
            unsigned short l = f32_to_bf16_rne(fv[j] - hf);
            a_hi_s[srow][scol + j] = (short)h;
            a_lo_s[srow][scol + j] = (short)l;
        }
        float s = fv[0]*fv[0] + fv[1]*fv[1] + fv[2]*fv[2] + fv[3]*fv[3];
        #pragma unroll
        for (int off = 1; off < 16; off <<= 1) s += __shfl_xor(s, off, 64);
        if ((tid & 15) == 0) zsq_s[srow] = s;
    }
    __syncthreads();

    // ---- A fragments: A[m][k], lane m holds k = kg*32 + qd*8 .. +8 ----
    bf16x8 ah[2], al[2];
    #pragma unroll
    for (int kg = 0; kg < 2; ++kg) {
        ah[kg] = *(const bf16x8*)&a_hi_s[m][kg * 32 + qd * 8];
        al[kg] = *(const bf16x8*)&a_lo_s[m][kg * 32 + qd * 8];
    }

    // ---- MFMA: cross = z_hi.c_hi + z_hi.c_lo + z_lo.c_hi (near-fp32) ----
    f32x4 acc[8];
    #pragma unroll
    for (int t = 0; t < 8; ++t) acc[t] = (f32x4){0.f, 0.f, 0.f, 0.f};
    #pragma unroll
    for (int kg = 0; kg < 2; ++kg) {
        #pragma unroll
        for (int t = 0; t < 8; ++t) {
            acc[t] = __builtin_amdgcn_mfma_f32_16x16x32_bf16(ah[kg], bh[t][kg], acc[t], 0, 0, 0);
            acc[t] = __builtin_amdgcn_mfma_f32_16x16x32_bf16(ah[kg], bl[t][kg], acc[t], 0, 0, 0);
            acc[t] = __builtin_amdgcn_mfma_f32_16x16x32_bf16(al[kg], bh[t][kg], acc[t], 0, 0, 0);
        }
    }

    // ---- dist = ||z||^2 + ||c||^2 - 2*cross -> LDS (C/D: col=lane&15, row=qd*4+r) ----
    #pragma unroll
    for (int t = 0; t < 8; ++t) {
        const int col = wave * 128 + t * 16 + m;
        const float csq = c_sq[col];
        #pragma unroll
        for (int r = 0; r < 4; ++r) {
            const int row = qd * 4 + r;
            dist_s[row][col] = zsq_s[row] + csq - 2.0f * acc[t][r];
        }
    }
    __syncthreads();

    // ---- softmax + q write + loss: wave handles rows [wave*4, wave*4+4) ----
    float lsum = 0.0f;
    #pragma unroll
    for (int rr = 0; rr < 4; ++rr) {
        const int row = wave * 4 + rr;
        float d[8];
        #pragma unroll
        for (int j = 0; j < 8; ++j) d[j] = dist_s[row][lane + 64 * j];
        float mn = d[0];
        #pragma unroll
        for (int j = 1; j < 8; ++j) mn = fminf(mn, d[j]);
        #pragma unroll
        for (int off = 1; off < 64; off <<= 1) mn = fminf(mn, __shfl_xor(mn, off, 64));
        float e[8], s = 0.0f;
        #pragma unroll
        for (int j = 0; j < 8; ++j) { e[j] = __expf(mn - d[j]); s += e[j]; }
        #pragma unroll
        for (int off = 1; off < 64; off <<= 1) s += __shfl_xor(s, off, 64);
        const float inv = 1.0f / s;
        float rl = 0.0f;
        float* orow = q_out + (rb + row) * K_CLUSTERS;
        #pragma unroll
        for (int j = 0; j < 8; ++j) {
            const float qv = e[j] * inv;
            orow[lane + 64 * j] = qv;     // 256B contiguous per store across wave
            rl += qv * d[j];
        }
        #pragma unroll
        for (int off = 1; off < 64; off <<= 1) rl += __shfl_xor(rl, off, 64);
        lsum += rl;
    }
    if (lane == 0) wloss_s[wave] = lsum;
    __syncthreads();
    if (tid == 0) partials[blockIdx.x] = wloss_s[0] + wloss_s[1] + wloss_s[2] + wloss_s[3];
}

__global__ void reduce_loss(const float* __restrict__ partials, int n,
                            float* __restrict__ loss_out, float inv_b) {
    float s = 0.f;
    for (int i = threadIdx.x; i < n; i += 256) s += partials[i];
    #pragma unroll
    for (int off = 1; off < 64; off <<= 1) s += __shfl_xor(s, off, 64);
    __shared__ float ws[4];
    if ((threadIdx.x & 63) == 0) ws[threadIdx.x >> 6] = s;
    __syncthreads();
    if (threadIdx.x == 0) loss_out[0] = (ws[0] + ws[1] + ws[2] + ws[3]) * inv_b;
}

extern "C" void kernel_launch(void* const* d_in, const int* in_sizes, int n_in,
                              void* d_out, int out_size, void* d_ws, size_t ws_size,
                              hipStream_t stream) {
    const float* z = (const float*)d_in[0];
    const float* c = (const float*)d_in[1];
    const int B = in_sizes[0] / DIM;              // 131072
    float* q_out = (float*)d_out;
    float* loss_out = q_out + (size_t)B * K_CLUSTERS;

    char* ws = (char*)d_ws;
    short* c_hi    = (short*)ws;                  // 64 KB
    short* c_lo    = (short*)(ws + 65536);        // 64 KB
    float* c_sq    = (float*)(ws + 131072);       // 2 KB
    float* partials = (float*)(ws + 133120);      // B/16 floats = 32 KB

    const int nblk = B / 16;
    prep_centers<<<(K_CLUSTERS * DIM) / 256, 256, 0, stream>>>(c, c_hi, c_lo, c_sq);
    cluster_kernel<<<nblk, 256, 0, stream>>>(z, c_hi, c_lo, c_sq, q_out, partials);
    reduce_loss<<<1, 256, 0, stream>>>(partials, nblk, loss_out, 1.0f / (float)B);
}

// Round 2
// 343.126 us; speedup vs baseline: 1.1531x; 1.1531x over previous
//
#include <hip/hip_runtime.h>

typedef short bf16x8 __attribute__((ext_vector_type(8)));
typedef float f32x4 __attribute__((ext_vector_type(4)));

#define K_CLUSTERS 512
#define DIM 64
#define ROWS_PER_BLOCK 64   // 4 subtiles of 16 rows; B fragments stay in registers

__device__ __forceinline__ unsigned short f32_to_bf16_rne(float f) {
    unsigned int u = __float_as_uint(f);
    u += 0x7fffu + ((u >> 16) & 1u);
    return (unsigned short)(u >> 16);
}
__device__ __forceinline__ float bf16_bits_to_f32(unsigned short h) {
    return __uint_as_float(((unsigned int)h) << 16);
}

// Convert centers to bf16 hi/lo split + compute ||c||^2. One wave per cluster.
__global__ void prep_centers(const float* __restrict__ c,
                             short* __restrict__ c_hi, short* __restrict__ c_lo,
                             float* __restrict__ c_sq) {
    int idx = blockIdx.x * 256 + threadIdx.x;   // covers 512*64
    float v = c[idx];
    unsigned short h = f32_to_bf16_rne(v);
    float hf = bf16_bits_to_f32(h);
    unsigned short l = f32_to_bf16_rne(v - hf);
    c_hi[idx] = (short)h;
    c_lo[idx] = (short)l;
    float s = v * v;
    #pragma unroll
    for (int off = 1; off < 64; off <<= 1) s += __shfl_xor(s, off, 64);
    if ((threadIdx.x & 63) == 0) c_sq[idx >> 6] = s;
}

__global__ void init_loss(float* __restrict__ loss_out) {
    if (threadIdx.x == 0) loss_out[0] = 0.0f;
}

// 64 rows per block in 4 subtiles of 16; 4 waves x 128 clusters each.
__global__ __launch_bounds__(256, 2)
void cluster_kernel(const float* __restrict__ z,
                    const short* __restrict__ c_hi,
                    const short* __restrict__ c_lo,
                    const float* __restrict__ c_sq,
                    float* __restrict__ q_out,
                    float* __restrict__ loss_out,
                    float inv_b) {
    __shared__ __align__(16) short a_hi_s[16][72];   // 144B rows: 16B-aligned
    __shared__ __align__(16) short a_lo_s[16][72];
    __shared__ float zsq_s[16];
    __shared__ float dist_s[16][K_CLUSTERS + 4];
    __shared__ float wloss_s[4];

    const int tid  = threadIdx.x;
    const int lane = tid & 63;
    const int wave = tid >> 6;
    const int m    = lane & 15;   // A row / B,C col within tile
    const int qd   = lane >> 4;   // quad
    const long rb  = (long)blockIdx.x * ROWS_PER_BLOCK;

    // ---- B fragments from global (bf16, L2-served). B[k][n] = c[n][k]:
    // lane n holds c[col][kg*32 + qd*8 .. +8) -> contiguous 16B.
    // Loaded ONCE per block, reused across 4 row-subtiles. ----
    bf16x8 bh[8][2], bl[8][2];
    float csq[8];
    #pragma unroll
    for (int t = 0; t < 8; ++t) {
        const int col = wave * 128 + t * 16 + m;
        const long boff = (long)col * DIM + qd * 8;
        #pragma unroll
        for (int kg = 0; kg < 2; ++kg) {
            bh[t][kg] = *(const bf16x8*)(c_hi + boff + kg * 32);
            bl[t][kg] = *(const bf16x8*)(c_lo + boff + kg * 32);
        }
        csq[t] = c_sq[col];
    }

    float4 v = ((const float4*)(z + rb * DIM))[tid];   // subtile 0 prefetch
    float lsum = 0.0f;

    for (int s = 0; s < ROWS_PER_BLOCK / 16; ++s) {
        float4 vn;
        if (s + 1 < ROWS_PER_BLOCK / 16)
            vn = ((const float4*)(z + (rb + (s + 1) * 16) * DIM))[tid];  // overlap w/ compute

        // ---- stage A subtile: 16 rows x 64 dims, fp32 -> bf16 hi/lo + ||z||^2 ----
        {
            const int srow = tid >> 4;
            const int scol = (tid & 15) * 4;
            float fv[4] = {v.x, v.y, v.z, v.w};
            #pragma unroll
            for (int j = 0; j < 4; ++j) {
                unsigned short h = f32_to_bf16_rne(fv[j]);
                float hf = bf16_bits_to_f32(h);
                unsigned short l = f32_to_bf16_rne(fv[j] - hf);
                a_hi_s[srow][scol + j] = (short)h;
                a_lo_s[srow][scol + j] = (short)l;
            }
            float ssq = fv[0]*fv[0] + fv[1]*fv[1] + fv[2]*fv[2] + fv[3]*fv[3];
            #pragma unroll
            for (int off = 1; off < 16; off <<= 1) ssq += __shfl_xor(ssq, off, 64);
            if ((tid & 15) == 0) zsq_s[srow] = ssq;
        }
        __syncthreads();   // sync1: A staged

        // ---- A fragments: lane m holds row m, k = kg*32 + qd*8 .. +8 ----
        bf16x8 ah[2], al[2];
        #pragma unroll
        for (int kg = 0; kg < 2; ++kg) {
            ah[kg] = *(const bf16x8*)&a_hi_s[m][kg * 32 + qd * 8];
            al[kg] = *(const bf16x8*)&a_lo_s[m][kg * 32 + qd * 8];
        }

        // ---- cross = z_hi.c_hi + z_hi.c_lo + z_lo.c_hi (near-fp32) ----
        f32x4 acc[8];
        #pragma unroll
        for (int t = 0; t < 8; ++t) acc[t] = (f32x4){0.f, 0.f, 0.f, 0.f};
        #pragma unroll
        for (int kg = 0; kg < 2; ++kg) {
            #pragma unroll
            for (int t = 0; t < 8; ++t) {
                acc[t] = __builtin_amdgcn_mfma_f32_16x16x32_bf16(ah[kg], bh[t][kg], acc[t], 0, 0, 0);
                acc[t] = __builtin_amdgcn_mfma_f32_16x16x32_bf16(ah[kg], bl[t][kg], acc[t], 0, 0, 0);
                acc[t] = __builtin_amdgcn_mfma_f32_16x16x32_bf16(al[kg], bh[t][kg], acc[t], 0, 0, 0);
            }
        }

        // ---- dist -> LDS (C/D: col=lane&15, row=qd*4+r) ----
        #pragma unroll
        for (int t = 0; t < 8; ++t) {
            const int col = wave * 128 + t * 16 + m;
            #pragma unroll
            for (int r = 0; r < 4; ++r) {
                const int row = qd * 4 + r;
                dist_s[row][col] = zsq_s[row] + csq[t] - 2.0f * acc[t][r];
            }
        }
        __syncthreads();   // sync2: dist complete; also fences A-frag reads

        // ---- softmax + q write + loss: wave handles rows [wave*4, wave*4+4) ----
        const long rbase = rb + s * 16;
        #pragma unroll
        for (int rr = 0; rr < 4; ++rr) {
            const int row = wave * 4 + rr;
            float d[8];
            #pragma unroll
            for (int j = 0; j < 8; ++j) d[j] = dist_s[row][lane + 64 * j];
            float mn = d[0];
            #pragma unroll
            for (int j = 1; j < 8; ++j) mn = fminf(mn, d[j]);
            #pragma unroll
            for (int off = 1; off < 64; off <<= 1) mn = fminf(mn, __shfl_xor(mn, off, 64));
            float e[8], ssum = 0.0f;
            #pragma unroll
            for (int j = 0; j < 8; ++j) { e[j] = __expf(mn - d[j]); ssum += e[j]; }
            #pragma unroll
            for (int off = 1; off < 64; off <<= 1) ssum += __shfl_xor(ssum, off, 64);
            const float inv = 1.0f / ssum;
            float rl = 0.0f;
            float* orow = q_out + (rbase + row) * K_CLUSTERS;
            #pragma unroll
            for (int j = 0; j < 8; ++j) {
                const float qv = e[j] * inv;
                orow[lane + 64 * j] = qv;
                rl += qv * d[j];
            }
            #pragma unroll
            for (int off = 1; off < 64; off <<= 1) rl += __shfl_xor(rl, off, 64);
            lsum += rl;
        }
        v = vn;
        // next iteration's sync1 orders softmax reads (this s) before dist writes (s+1);
        // a_hi_s/a_lo_s writes (s+1) only conflict with frag reads (s), fenced by sync2.
    }

    if (lane == 0) wloss_s[wave] = lsum;
    __syncthreads();
    if (tid == 0)
        atomicAdd(loss_out, (wloss_s[0] + wloss_s[1] + wloss_s[2] + wloss_s[3]) * inv_b);
}

extern "C" void kernel_launch(void* const* d_in, const int* in_sizes, int n_in,
                              void* d_out, int out_size, void* d_ws, size_t ws_size,
                              hipStream_t stream) {
    const float* z = (const float*)d_in[0];
    const float* c = (const float*)d_in[1];
    const int B = in_sizes[0] / DIM;              // 131072
    float* q_out = (float*)d_out;
    float* loss_out = q_out + (size_t)B * K_CLUSTERS;

    char* ws = (char*)d_ws;
    short* c_hi = (short*)ws;                     // 64 KB
    short* c_lo = (short*)(ws + 65536);           // 64 KB
    float* c_sq = (float*)(ws + 131072);          // 2 KB

    prep_centers<<<(K_CLUSTERS * DIM) / 256, 256, 0, stream>>>(c, c_hi, c_lo, c_sq);
    init_loss<<<1, 64, 0, stream>>>(loss_out);
    cluster_kernel<<<B / ROWS_PER_BLOCK, 256, 0, stream>>>(z, c_hi, c_lo, c_sq, q_out,
                                                           loss_out, 1.0f / (float)B);
}

// Round 3
// 342.246 us; speedup vs baseline: 1.1561x; 1.0026x over previous
//
#include <hip/hip_runtime.h>

typedef short bf16x8 __attribute__((ext_vector_type(8)));
typedef float f32x4 __attribute__((ext_vector_type(4)));

#define K_CLUSTERS 512
#define DIM 64
#define ROWS_PER_BLOCK 64   // 4 subtiles of 16 rows

__device__ __forceinline__ unsigned short f32_to_bf16_rne(float f) {
    unsigned int u = __float_as_uint(f);
    u += 0x7fffu + ((u >> 16) & 1u);
    return (unsigned short)(u >> 16);
}
__device__ __forceinline__ float bf16_bits_to_f32(unsigned short h) {
    return __uint_as_float(((unsigned int)h) << 16);
}

// Centers -> bf16 hi/lo split + ||c||^2. Also zero-inits the loss accumulator.
__global__ void prep_centers(const float* __restrict__ c,
                             short* __restrict__ c_hi, short* __restrict__ c_lo,
                             float* __restrict__ c_sq, float* __restrict__ loss_out) {
    if (blockIdx.x == 0 && threadIdx.x == 0) loss_out[0] = 0.0f;
    int idx = blockIdx.x * 256 + threadIdx.x;   // covers 512*64
    float v = c[idx];
    unsigned short h = f32_to_bf16_rne(v);
    float hf = bf16_bits_to_f32(h);
    unsigned short l = f32_to_bf16_rne(v - hf);
    c_hi[idx] = (short)h;
    c_lo[idx] = (short)l;
    float s = v * v;
    #pragma unroll
    for (int off = 1; off < 64; off <<= 1) s += __shfl_xor(s, off, 64);
    if ((threadIdx.x & 63) == 0) c_sq[idx >> 6] = s;
}

// 64 rows/block in 4 subtiles of 16; 8 waves x 64 clusters each.
// launch_bounds(512,4): cap VGPR at 128 -> 2 blocks/CU -> 16 waves/CU.
__global__ __launch_bounds__(512, 4)
void cluster_kernel(const float* __restrict__ z,
                    const short* __restrict__ c_hi,
                    const short* __restrict__ c_lo,
                    const float* __restrict__ c_sq,
                    float* __restrict__ q_out,
                    float* __restrict__ loss_out,
                    float inv_b) {
    __shared__ __align__(16) short a_hi_s[16][72];   // 144B rows: 16B-aligned
    __shared__ __align__(16) short a_lo_s[16][72];
    __shared__ float zsq_s[16];
    __shared__ float dist_s[16][K_CLUSTERS + 4];
    __shared__ float wloss_s[8];

    const int tid  = threadIdx.x;
    const int lane = tid & 63;
    const int wave = tid >> 6;
    const int m    = lane & 15;   // A row / B,C col within tile
    const int qd   = lane >> 4;   // quad
    const long rb  = (long)blockIdx.x * ROWS_PER_BLOCK;

    // ---- B fragments (64 cols/wave = 4 tiles): 64 VGPRs each hi+lo half. ----
    bf16x8 bh[4][2], bl[4][2];
    float csq[4];
    #pragma unroll
    for (int t = 0; t < 4; ++t) {
        const int col = wave * 64 + t * 16 + m;
        const long boff = (long)col * DIM + qd * 8;
        #pragma unroll
        for (int kg = 0; kg < 2; ++kg) {
            bh[t][kg] = *(const bf16x8*)(c_hi + boff + kg * 32);
            bl[t][kg] = *(const bf16x8*)(c_lo + boff + kg * 32);
        }
        csq[t] = c_sq[col];
    }

    const float2* zin = (const float2*)(z + rb * DIM);   // 16 rows x 64 = 512 float2
    float2 v = zin[tid];
    float lsum = 0.0f;

    for (int s = 0; s < ROWS_PER_BLOCK / 16; ++s) {
        float2 vn;
        if (s + 1 < ROWS_PER_BLOCK / 16) vn = zin[(s + 1) * 512 + tid];

        // ---- stage A subtile: fp32 -> bf16 hi/lo + ||z||^2 (32 threads/row) ----
        {
            const int srow = tid >> 5;
            const int scol = (tid & 31) * 2;
            float fv[2] = {v.x, v.y};
            #pragma unroll
            for (int j = 0; j < 2; ++j) {
                unsigned short h = f32_to_bf16_rne(fv[j]);
                float hf = bf16_bits_to_f32(h);
                unsigned short l = f32_to_bf16_rne(fv[j] - hf);
                a_hi_s[srow][scol + j] = (short)h;
                a_lo_s[srow][scol + j] = (short)l;
            }
            float ssq = fv[0] * fv[0] + fv[1] * fv[1];
            #pragma unroll
            for (int off = 1; off < 32; off <<= 1) ssq += __shfl_xor(ssq, off, 64);
            if ((tid & 31) == 0) zsq_s[srow] = ssq;
        }
        __syncthreads();   // sync1: A staged

        // ---- A fragments: lane m holds row m, k = kg*32 + qd*8 .. +8 ----
        bf16x8 ah[2], al[2];
        #pragma unroll
        for (int kg = 0; kg < 2; ++kg) {
            ah[kg] = *(const bf16x8*)&a_hi_s[m][kg * 32 + qd * 8];
            al[kg] = *(const bf16x8*)&a_lo_s[m][kg * 32 + qd * 8];
        }

        // ---- cross = z_hi.c_hi + z_hi.c_lo + z_lo.c_hi (near-fp32) ----
        f32x4 acc[4];
        #pragma unroll
        for (int t = 0; t < 4; ++t) acc[t] = (f32x4){0.f, 0.f, 0.f, 0.f};
        #pragma unroll
        for (int kg = 0; kg < 2; ++kg) {
            #pragma unroll
            for (int t = 0; t < 4; ++t) {
                acc[t] = __builtin_amdgcn_mfma_f32_16x16x32_bf16(ah[kg], bh[t][kg], acc[t], 0, 0, 0);
                acc[t] = __builtin_amdgcn_mfma_f32_16x16x32_bf16(ah[kg], bl[t][kg], acc[t], 0, 0, 0);
                acc[t] = __builtin_amdgcn_mfma_f32_16x16x32_bf16(al[kg], bh[t][kg], acc[t], 0, 0, 0);
            }
        }

        // ---- dist -> LDS (C/D: col=lane&15, row=qd*4+r) ----
        #pragma unroll
        for (int t = 0; t < 4; ++t) {
            const int col = wave * 64 + t * 16 + m;
            #pragma unroll
            for (int r = 0; r < 4; ++r) {
                const int row = qd * 4 + r;
                dist_s[row][col] = zsq_s[row] + csq[t] - 2.0f * acc[t][r];
            }
        }
        __syncthreads();   // sync2: dist complete; also fences A-frag reads

        // ---- softmax + q write: wave handles rows [wave*2, wave*2+2).
        //      Loss: per-lane partial only (reduced once at kernel end). ----
        const long rbase = rb + s * 16;
        #pragma unroll
        for (int rr = 0; rr < 2; ++rr) {
            const int row = wave * 2 + rr;
            float d[8];
            #pragma unroll
            for (int j = 0; j < 8; ++j) d[j] = dist_s[row][lane + 64 * j];
            float mn = d[0];
            #pragma unroll
            for (int j = 1; j < 8; ++j) mn = fminf(mn, d[j]);
            #pragma unroll
            for (int off = 1; off < 64; off <<= 1) mn = fminf(mn, __shfl_xor(mn, off, 64));
            float e[8], ssum = 0.0f;
            #pragma unroll
            for (int j = 0; j < 8; ++j) { e[j] = __expf(mn - d[j]); ssum += e[j]; }
            #pragma unroll
            for (int off = 1; off < 64; off <<= 1) ssum += __shfl_xor(ssum, off, 64);
            const float inv = 1.0f / ssum;
            float rl = 0.0f;
            float* orow = q_out + (rbase + row) * K_CLUSTERS;
            #pragma unroll
            for (int j = 0; j < 8; ++j) {
                const float qv = e[j] * inv;
                __builtin_nontemporal_store(qv, orow + lane + 64 * j);  // write-once stream
                rl += qv * d[j];
            }
            lsum += rl;   // per-lane partial; cross-lane deferred
        }
        v = vn;
    }

    // ---- final loss reduction: one 64-lane shuffle tree per wave ----
    #pragma unroll
    for (int off = 1; off < 64; off <<= 1) lsum += __shfl_xor(lsum, off, 64);
    if (lane == 0) wloss_s[wave] = lsum;
    __syncthreads();
    if (tid == 0) {
        float t0 = 0.f;
        #pragma unroll
        for (int w = 0; w < 8; ++w) t0 += wloss_s[w];
        atomicAdd(loss_out, t0 * inv_b);
    }
}

extern "C" void kernel_launch(void* const* d_in, const int* in_sizes, int n_in,
                              void* d_out, int out_size, void* d_ws, size_t ws_size,
                              hipStream_t stream) {
    const float* z = (const float*)d_in[0];
    const float* c = (const float*)d_in[1];
    const int B = in_sizes[0] / DIM;              // 131072
    float* q_out = (float*)d_out;
    float* loss_out = q_out + (size_t)B * K_CLUSTERS;

    char* ws = (char*)d_ws;
    short* c_hi = (short*)ws;                     // 64 KB
    short* c_lo = (short*)(ws + 65536);           // 64 KB
    float* c_sq = (float*)(ws + 131072);          // 2 KB

    prep_centers<<<(K_CLUSTERS * DIM) / 256, 256, 0, stream>>>(c, c_hi, c_lo, c_sq, loss_out);
    cluster_kernel<<<B / ROWS_PER_BLOCK, 512, 0, stream>>>(z, c_hi, c_lo, c_sq, q_out,
                                                           loss_out, 1.0f / (float)B);
}